// Round 1
// baseline (15715.788 us; speedup 1.0000x reference)
//
#include <hip/hip_runtime.h>
#include <stdint.h>
#include <stddef.h>

#define B_  64
#define T_  256
#define H_  1024
#define AS_ 128
#define L_  3

typedef __attribute__((ext_vector_type(8))) short bf16x8;
typedef __attribute__((ext_vector_type(4))) float f32x4;

__device__ __forceinline__ unsigned short f2bf(float f) {
  union { float f; unsigned u; } x; x.f = f;
  unsigned r = x.u + 0x7fffu + ((x.u >> 16) & 1u);   // RNE
  return (unsigned short)(r >> 16);
}
__device__ __forceinline__ float bf2f(unsigned short s) {
  union { unsigned u; float f; } x; x.u = ((unsigned)s) << 16; return x.f;
}
__device__ __forceinline__ float sigmf(float x) { return 1.0f / (1.0f + __expf(-x)); }
__device__ __forceinline__ float tanh_f(float x) {
  x = fminf(fmaxf(x, -15.0f), 15.0f);
  float e = __expf(2.0f * x);
  return (e - 1.0f) / (e + 1.0f);
}

// ---------------- tiny utility kernels ----------------

__global__ void k_zero(unsigned* p, int n) {
  int i = blockIdx.x * 256 + threadIdx.x;
  if (i < n) p[i] = 0u;
}

// Wt[a][h] = bf16(W_i2h[h][a] + b_i2h[h])   (128 x 1024)
__global__ void k_wt_i2h(const float* __restrict__ W, const float* __restrict__ b,
                         unsigned short* __restrict__ Wt) {
  int id = blockIdx.x * 256 + threadIdx.x;        // a*1024 + h
  if (id >= AS_ * H_) return;
  int a = id >> 10, h = id & 1023;
  Wt[id] = f2bf(W[h * AS_ + a] + b[h]);
}

__global__ void k_f2b(const float* __restrict__ s, unsigned short* __restrict__ d, int n) {
  int i = blockIdx.x * 256 + threadIdx.x;
  if (i < n) d[i] = f2bf(s[i]);
}

__global__ void k_bias(const float* __restrict__ bi, const float* __restrict__ bh,
                       float* __restrict__ o, int n) {
  int i = blockIdx.x * 256 + threadIdx.x;
  if (i < n) o[i] = bi[i] + bh[i];
}

// one block (128 threads) per (b,t): find one-hot index, copy Wt row to x_bf
__global__ __launch_bounds__(128) void k_gather(const float* __restrict__ seq,
                                                const unsigned short* __restrict__ Wt,
                                                unsigned short* __restrict__ xbf) {
  __shared__ int sidx;
  const int bt = blockIdx.x, tid = threadIdx.x;
  if (seq[(size_t)bt * AS_ + tid] > 0.5f) sidx = tid;
  __syncthreads();
  const uint4* s = (const uint4*)(Wt + (size_t)sidx * H_);
  uint4* d = (uint4*)(xbf + (size_t)bt * H_);
  d[tid] = s[tid];   // 128 * 16B = 2048B row
}

// ---------------- MFMA GEMM: C[m][n] = sum_k A[m][k]*B[n][k] + bias[n] ----------------
// A: [M][K] bf16 row-major, B: [N][K] bf16 row-major. 128x128 tile, BK=32, m97-style
// global_load_lds staging with source-pre-swizzled chunks (T2-lite).

__device__ __forceinline__ void gld16(const void* g, void* l) {
  __builtin_amdgcn_global_load_lds((const __attribute__((address_space(1))) unsigned int*)g,
                                   (__attribute__((address_space(3))) unsigned int*)l,
                                   16, 0, 0);
}

template <int OUT_BF16>
__global__ __launch_bounds__(256) void k_gemm(const unsigned short* __restrict__ A,
                                              const unsigned short* __restrict__ Bm,
                                              const float* __restrict__ bias,
                                              void* __restrict__ Cout,
                                              int M, int N, int K) {
  __shared__ __align__(16) unsigned short As[128 * 32];
  __shared__ __align__(16) unsigned short Bs[128 * 32];
  const int tid = threadIdx.x, lane = tid & 63, wv = tid >> 6;
  const int m0 = blockIdx.x * 128, n0 = blockIdx.y * 128;
  const int wr = wv >> 1, wc = wv & 1;
  const int kg = lane >> 4, li = lane & 15;
  f32x4 acc[4][4] = {};

  for (int k0 = 0; k0 < K; k0 += 32) {
    // stage 512 16B chunks per matrix; LDS linear dest, swizzled global source
    for (int i = 0; i < 2; ++i) {
      int c0 = i * 256 + wv * 64;            // wave-uniform chunk base
      int cid = c0 + lane;
      int row = cid >> 2, lc = cid & 3;
      int sc = lc ^ ((row >> 1) & 3);
      gld16(A + (size_t)(m0 + row) * K + k0 + sc * 8, (char*)As + (size_t)c0 * 16);
      gld16(Bm + (size_t)(n0 + row) * K + k0 + sc * 8, (char*)Bs + (size_t)c0 * 16);
    }
    __syncthreads();
    bf16x8 af[4], bfm[4];
#pragma unroll
    for (int mi = 0; mi < 4; ++mi) {
      int row = wr * 64 + mi * 16 + li;
      int pc = kg ^ ((row >> 1) & 3);
      af[mi] = *(const bf16x8*)((const char*)As + row * 64 + pc * 16);
    }
#pragma unroll
    for (int ni = 0; ni < 4; ++ni) {
      int row = wc * 64 + ni * 16 + li;
      int pc = kg ^ ((row >> 1) & 3);
      bfm[ni] = *(const bf16x8*)((const char*)Bs + row * 64 + pc * 16);
    }
#pragma unroll
    for (int mi = 0; mi < 4; ++mi)
#pragma unroll
      for (int ni = 0; ni < 4; ++ni)
        acc[mi][ni] = __builtin_amdgcn_mfma_f32_16x16x32_bf16(af[mi], bfm[ni], acc[mi][ni], 0, 0, 0);
    __syncthreads();
  }

#pragma unroll
  for (int mi = 0; mi < 4; ++mi)
#pragma unroll
    for (int ni = 0; ni < 4; ++ni)
#pragma unroll
      for (int r = 0; r < 4; ++r) {
        int row = m0 + wr * 64 + mi * 16 + kg * 4 + r;
        int col = n0 + wc * 64 + ni * 16 + li;
        float v = acc[mi][ni][r] + bias[col];
        if (OUT_BF16) ((unsigned short*)Cout)[(size_t)row * N + col] = f2bf(v);
        else          ((float*)Cout)[(size_t)row * N + col] = v;
      }
}

// ---------------- persistent LSTM scan ----------------
// 256 wgs (1/CU). wg = (gb: batch group of 16, ug: unit group of 16).
// W_hh rows {g*1024 + ug*16 + u} held in LDS bf16 (XOR-swizzled, 128KB).
// Per step: wave g computes gates[g] for 16 batches x 16 units via MFMA chain;
// wave 0 applies the cell update (c in registers); flag-array barrier per step
// scoped to the 64 wgs of a batch group.

__global__ __launch_bounds__(256, 1) void k_scan(const unsigned short* __restrict__ xg,   // [B*T][4H] bf16 (bias folded)
                                                 const float* __restrict__ Whh,           // [4H][H] f32
                                                 unsigned short* __restrict__ h_pp,       // [2][B][H] bf16
                                                 unsigned short* __restrict__ out_seq,    // [B*T][H] bf16 or null
                                                 float* __restrict__ hT, float* __restrict__ cT,
                                                 const float* __restrict__ h0, const float* __restrict__ c0,
                                                 unsigned* __restrict__ flags) {          // [256] this layer
  __shared__ __align__(16) unsigned short Wlds[4 * 16 * 1024];  // 128 KB
  __shared__ float gx[4][64][4];                                // 4 KB
  const int tid = threadIdx.x, lane = tid & 63, wave = tid >> 6;
  const int wg = blockIdx.x, gb = wg >> 6, ug = wg & 63;
  const int li = lane & 15, kq = lane >> 4;

  // ---- load W_hh slice -> LDS bf16, swizzled: byte = (wave*16+u)*2048 + (2k ^ ((u&7)<<4))
  for (int it = 0; it < 64; ++it) {
    int idx = it * 256 + lane * 4;            // covers 16*1024 per wave
    int u = idx >> 10, k = idx & 1023;
    const float4 w = *(const float4*)&Whh[((size_t)(wave * H_ + ug * 16 + u)) * H_ + k];
    ushort4 p; p.x = f2bf(w.x); p.y = f2bf(w.y); p.z = f2bf(w.z); p.w = f2bf(w.w);
    *(ushort4*)((char*)Wlds + (size_t)(wave * 16 + u) * 2048 + ((2 * k) ^ ((u & 7) << 4))) = p;
  }
  // ---- init h buf1 from h0 (read at t=0), c from c0
  {
    int b = gb * 16 + (tid >> 4), u = ug * 16 + (tid & 15);
    h_pp[(size_t)(B_ + b) * H_ + u] = f2bf(h0[(size_t)b * H_ + u]);
  }
  float c_st[4];
#pragma unroll
  for (int r = 0; r < 4; ++r)
    c_st[r] = c0[(size_t)(gb * 16 + kq * 4 + r) * H_ + ug * 16 + li];

  unsigned ep = 1;
  // group barrier (64 wgs of this gb)
  auto gbar = [&](unsigned e) {
    __syncthreads();
    if (wave == 0) {
      __threadfence();
      if (lane == 0) __hip_atomic_store(&flags[wg], e, __ATOMIC_RELEASE, __HIP_MEMORY_SCOPE_AGENT);
      unsigned v;
      do {
        __builtin_amdgcn_s_sleep(1);
        v = __hip_atomic_load(&flags[(gb << 6) + lane], __ATOMIC_RELAXED, __HIP_MEMORY_SCOPE_AGENT);
      } while (__any((int)(v < e)));
      __threadfence();
    }
    __syncthreads();
  };
  gbar(ep); ep++;

  const char* bbase = (const char*)Wlds + (size_t)(wave * 16 + li) * 2048;
  const int bxor = (li & 7) << 4;

  for (int t = 0; t < T_; ++t) {
    const unsigned short* hrd = h_pp + (size_t)((t & 1) ^ 1) * (B_ * H_);
    unsigned short* hwr = h_pp + (size_t)(t & 1) * (B_ * H_);

    // prefetch xg for this step (overlaps MFMA chain)
    float xv[4];
#pragma unroll
    for (int r = 0; r < 4; ++r) {
      int bm = gb * 16 + kq * 4 + r;
      xv[r] = bf2f(xg[((size_t)bm * T_ + t) * (4 * H_) + (size_t)wave * H_ + ug * 16 + li]);
    }

    f32x4 acc = {0.f, 0.f, 0.f, 0.f};
    const unsigned short* aptr = hrd + (size_t)(gb * 16 + li) * H_ + kq * 8;
#pragma unroll 8
    for (int ks = 0; ks < 32; ++ks) {
      bf16x8 af = *(const bf16x8*)(aptr + ks * 32);
      bf16x8 bv = *(const bf16x8*)(bbase + ((ks * 64 + kq * 16) ^ bxor));
      acc = __builtin_amdgcn_mfma_f32_16x16x32_bf16(af, bv, acc, 0, 0, 0);
    }
#pragma unroll
    for (int r = 0; r < 4; ++r) gx[wave][lane][r] = acc[r] + xv[r];
    __syncthreads();

    if (wave == 0) {
#pragma unroll
      for (int r = 0; r < 4; ++r) {
        float gi = gx[0][lane][r], gf = gx[1][lane][r], gg = gx[2][lane][r], go = gx[3][lane][r];
        float ci = sigmf(gf) * c_st[r] + sigmf(gi) * tanh_f(gg);
        c_st[r] = ci;
        float h = sigmf(go) * tanh_f(ci);
        int bm = gb * 16 + kq * 4 + r, uu = ug * 16 + li;
        hwr[(size_t)bm * H_ + uu] = f2bf(h);
        if (out_seq) out_seq[((size_t)bm * T_ + t) * H_ + uu] = f2bf(h);
        if (t == T_ - 1) {
          hT[(size_t)bm * H_ + uu] = h;
          cT[(size_t)bm * H_ + uu] = ci;
        }
      }
    }
    gbar(ep); ep++;
  }
}

// ---------------- launcher ----------------

extern "C" void kernel_launch(void* const* d_in, const int* in_sizes, int n_in,
                              void* d_out, int out_size, void* d_ws, size_t ws_size,
                              hipStream_t stream) {
  const float* seq  = (const float*)d_in[0];
  const float* Wi2h = (const float*)d_in[1];
  const float* bi2h = (const float*)d_in[2];
  const float* Wih  = (const float*)d_in[3];
  const float* Whh  = (const float*)d_in[4];
  const float* bih  = (const float*)d_in[5];
  const float* bhh  = (const float*)d_in[6];
  const float* Wh2o = (const float*)d_in[7];
  const float* bh2o = (const float*)d_in[8];
  const float* h0   = (const float*)d_in[9];
  const float* c0   = (const float*)d_in[10];
  float* outF = (float*)d_out;

  // ws layout (~217 MiB total)
  size_t off = 0;
  auto nb = [&](size_t bytes) { size_t r = off; off += (bytes + 255) & ~(size_t)255; return r; };
  unsigned short* xbf   = (unsigned short*)((char*)d_ws + nb((size_t)B_ * T_ * H_ * 2));       // 32MB
  unsigned short* seqA  = (unsigned short*)((char*)d_ws + nb((size_t)B_ * T_ * H_ * 2));       // 32MB
  unsigned short* xg    = (unsigned short*)((char*)d_ws + nb((size_t)B_ * T_ * 4 * H_ * 2));   // 128MB
  unsigned short* Wihb  = (unsigned short*)((char*)d_ws + nb((size_t)L_ * 4 * H_ * H_ * 2));   // 24MB
  unsigned short* Wh2ob = (unsigned short*)((char*)d_ws + nb((size_t)AS_ * H_ * 2));
  unsigned short* Wt    = (unsigned short*)((char*)d_ws + nb((size_t)AS_ * H_ * 2));
  float*          bsum  = (float*)((char*)d_ws + nb((size_t)L_ * 4 * H_ * 4));
  unsigned short* h_pp  = (unsigned short*)((char*)d_ws + nb((size_t)2 * B_ * H_ * 2));
  unsigned*       flg   = (unsigned*)((char*)d_ws + nb((size_t)L_ * 256 * 4));
  (void)ws_size; (void)in_sizes; (void)n_in; (void)out_size;

  const int WLAYER = 4 * H_ * H_;  // 4,194,304 elements per layer weight

  k_zero<<<3, 256, 0, stream>>>(flg, L_ * 256);
  k_wt_i2h<<<(AS_ * H_ + 255) / 256, 256, 0, stream>>>(Wi2h, bi2h, Wt);
  k_f2b<<<(L_ * WLAYER + 255) / 256, 256, 0, stream>>>(Wih, Wihb, L_ * WLAYER);
  k_f2b<<<(AS_ * H_ + 255) / 256, 256, 0, stream>>>(Wh2o, Wh2ob, AS_ * H_);
  k_bias<<<(L_ * 4 * H_ + 255) / 256, 256, 0, stream>>>(bih, bhh, bsum, L_ * 4 * H_);
  k_gather<<<B_ * T_, 128, 0, stream>>>(seq, Wt, xbf);

  // out = x @ W_h2O^T + b  (faithful to reference bug: uses x, not LSTM output)
  k_gemm<0><<<dim3(B_ * T_ / 128, AS_ / 128), 256, 0, stream>>>(
      xbf, Wh2ob, bh2o, (void*)outF, B_ * T_, AS_, H_);

  float* hT_base = outF + (size_t)B_ * T_ * AS_;             // 2,097,152
  float* cT_base = hT_base + (size_t)L_ * B_ * H_;           // +196,608

  for (int l = 0; l < L_; ++l) {
    const unsigned short* Ain = (l == 0) ? xbf : (l == 1) ? seqA : xbf;
    unsigned short* oseq = (l == 0) ? seqA : (l == 1) ? xbf : nullptr;
    k_gemm<1><<<dim3(B_ * T_ / 128, 4 * H_ / 128), 256, 0, stream>>>(
        Ain, Wihb + (size_t)l * WLAYER, bsum + (size_t)l * 4 * H_, (void*)xg,
        B_ * T_, 4 * H_, H_);
    k_scan<<<256, 256, 0, stream>>>(
        xg, Whh + (size_t)l * WLAYER, h_pp, oseq,
        hT_base + (size_t)l * B_ * H_, cT_base + (size_t)l * B_ * H_,
        h0 + (size_t)l * B_ * H_, c0 + (size_t)l * B_ * H_,
        flg + (size_t)l * 256);
  }
}

// Round 2
// 7362.389 us; speedup vs baseline: 2.1346x; 2.1346x over previous
//
#include <hip/hip_runtime.h>
#include <stdint.h>
#include <stddef.h>

#define B_  64
#define T_  256
#define H_  1024
#define AS_ 128
#define L_  3

typedef __attribute__((ext_vector_type(8))) short bf16x8;
typedef __attribute__((ext_vector_type(4))) float f32x4;

__device__ __forceinline__ unsigned short f2bf(float f) {
  union { float f; unsigned u; } x; x.f = f;
  unsigned r = x.u + 0x7fffu + ((x.u >> 16) & 1u);   // RNE
  return (unsigned short)(r >> 16);
}
__device__ __forceinline__ float bf2f(unsigned short s) {
  union { unsigned u; float f; } x; x.u = ((unsigned)s) << 16; return x.f;
}
__device__ __forceinline__ float sigmf(float x) { return 1.0f / (1.0f + __expf(-x)); }
__device__ __forceinline__ float tanh_f(float x) {
  x = fminf(fmaxf(x, -15.0f), 15.0f);
  float e = __expf(2.0f * x);
  return (e - 1.0f) / (e + 1.0f);
}

// ---- cache-bypassing (device-coherent) accessors: relaxed agent atomics ----
__device__ __forceinline__ unsigned long long ld_u64_cc(const void* p) {
  return __hip_atomic_load((const unsigned long long*)p, __ATOMIC_RELAXED, __HIP_MEMORY_SCOPE_AGENT);
}
__device__ __forceinline__ void st_u16_cc(unsigned short* p, unsigned short v) {
  __hip_atomic_store(p, v, __ATOMIC_RELAXED, __HIP_MEMORY_SCOPE_AGENT);
}
__device__ __forceinline__ void st_u32_cc(unsigned* p, unsigned v) {
  __hip_atomic_store(p, v, __ATOMIC_RELAXED, __HIP_MEMORY_SCOPE_AGENT);
}
__device__ __forceinline__ unsigned ld_u32_cc(const unsigned* p) {
  return __hip_atomic_load(p, __ATOMIC_RELAXED, __HIP_MEMORY_SCOPE_AGENT);
}

// ---------------- tiny utility kernels ----------------

__global__ void k_zero(unsigned* p, int n) {
  int i = blockIdx.x * 256 + threadIdx.x;
  if (i < n) st_u32_cc(p + i, 0u);   // bypass store: readers bypass L2, so must we
}

// Wt[a][h] = bf16(W_i2h[h][a] + b_i2h[h])   (128 x 1024)
__global__ void k_wt_i2h(const float* __restrict__ W, const float* __restrict__ b,
                         unsigned short* __restrict__ Wt) {
  int id = blockIdx.x * 256 + threadIdx.x;        // a*1024 + h
  if (id >= AS_ * H_) return;
  int a = id >> 10, h = id & 1023;
  Wt[id] = f2bf(W[h * AS_ + a] + b[h]);
}

__global__ void k_f2b(const float* __restrict__ s, unsigned short* __restrict__ d, int n) {
  int i = blockIdx.x * 256 + threadIdx.x;
  if (i < n) d[i] = f2bf(s[i]);
}

__global__ void k_bias(const float* __restrict__ bi, const float* __restrict__ bh,
                       float* __restrict__ o, int n) {
  int i = blockIdx.x * 256 + threadIdx.x;
  if (i < n) o[i] = bi[i] + bh[i];
}

// one block (128 threads) per (b,t): find one-hot index, copy Wt row to x_bf
__global__ __launch_bounds__(128) void k_gather(const float* __restrict__ seq,
                                                const unsigned short* __restrict__ Wt,
                                                unsigned short* __restrict__ xbf) {
  __shared__ int sidx;
  const int bt = blockIdx.x, tid = threadIdx.x;
  if (seq[(size_t)bt * AS_ + tid] > 0.5f) sidx = tid;
  __syncthreads();
  const uint4* s = (const uint4*)(Wt + (size_t)sidx * H_);
  uint4* d = (uint4*)(xbf + (size_t)bt * H_);
  d[tid] = s[tid];   // 128 * 16B = 2048B row
}

// ---------------- MFMA GEMM: C[m][n] = sum_k A[m][k]*B[n][k] + bias[n] ----------------

__device__ __forceinline__ void gld16(const void* g, void* l) {
  __builtin_amdgcn_global_load_lds((const __attribute__((address_space(1))) unsigned int*)g,
                                   (__attribute__((address_space(3))) unsigned int*)l,
                                   16, 0, 0);
}

template <int OUT_BF16>
__global__ __launch_bounds__(256) void k_gemm(const unsigned short* __restrict__ A,
                                              const unsigned short* __restrict__ Bm,
                                              const float* __restrict__ bias,
                                              void* __restrict__ Cout,
                                              int M, int N, int K) {
  __shared__ __align__(16) unsigned short As[128 * 32];
  __shared__ __align__(16) unsigned short Bs[128 * 32];
  const int tid = threadIdx.x, lane = tid & 63, wv = tid >> 6;
  const int m0 = blockIdx.x * 128, n0 = blockIdx.y * 128;
  const int wr = wv >> 1, wc = wv & 1;
  const int kg = lane >> 4, li = lane & 15;
  f32x4 acc[4][4] = {};

  for (int k0 = 0; k0 < K; k0 += 32) {
    for (int i = 0; i < 2; ++i) {
      int c0 = i * 256 + wv * 64;            // wave-uniform chunk base
      int cid = c0 + lane;
      int row = cid >> 2, lc = cid & 3;
      int sc = lc ^ ((row >> 1) & 3);
      gld16(A + (size_t)(m0 + row) * K + k0 + sc * 8, (char*)As + (size_t)c0 * 16);
      gld16(Bm + (size_t)(n0 + row) * K + k0 + sc * 8, (char*)Bs + (size_t)c0 * 16);
    }
    __syncthreads();
    bf16x8 af[4], bfm[4];
#pragma unroll
    for (int mi = 0; mi < 4; ++mi) {
      int row = wr * 64 + mi * 16 + li;
      int pc = kg ^ ((row >> 1) & 3);
      af[mi] = *(const bf16x8*)((const char*)As + row * 64 + pc * 16);
    }
#pragma unroll
    for (int ni = 0; ni < 4; ++ni) {
      int row = wc * 64 + ni * 16 + li;
      int pc = kg ^ ((row >> 1) & 3);
      bfm[ni] = *(const bf16x8*)((const char*)Bs + row * 64 + pc * 16);
    }
#pragma unroll
    for (int mi = 0; mi < 4; ++mi)
#pragma unroll
      for (int ni = 0; ni < 4; ++ni)
        acc[mi][ni] = __builtin_amdgcn_mfma_f32_16x16x32_bf16(af[mi], bfm[ni], acc[mi][ni], 0, 0, 0);
    __syncthreads();
  }

#pragma unroll
  for (int mi = 0; mi < 4; ++mi)
#pragma unroll
    for (int ni = 0; ni < 4; ++ni)
#pragma unroll
      for (int r = 0; r < 4; ++r) {
        int row = m0 + wr * 64 + mi * 16 + kg * 4 + r;
        int col = n0 + wc * 64 + ni * 16 + li;
        float v = acc[mi][ni][r] + bias[col];
        if (OUT_BF16) ((unsigned short*)Cout)[(size_t)row * N + col] = f2bf(v);
        else          ((float*)Cout)[(size_t)row * N + col] = v;
      }
}

// ---------------- persistent LSTM scan (fence-free barrier protocol) ----------------
// 256 wgs (1/CU). wg = (gb: batch group of 16, ug: unit group of 16).
// All cross-wg data moves through relaxed agent atomics (sc1 cache-bypass);
// __syncthreads' built-in vmcnt(0) drain orders h stores before the flag store.

__global__ __launch_bounds__(256, 1) void k_scan(const unsigned short* __restrict__ xg,   // [B*T][4H] bf16
                                                 const float* __restrict__ Whh,           // [4H][H] f32
                                                 unsigned short* __restrict__ h_pp,       // [2][B][H] bf16
                                                 unsigned short* __restrict__ out_seq,    // [B*T][H] bf16 or null
                                                 float* __restrict__ hT, float* __restrict__ cT,
                                                 const float* __restrict__ h0, const float* __restrict__ c0,
                                                 unsigned* __restrict__ flags) {          // [256] this layer
  __shared__ __align__(16) unsigned short Wlds[4 * 16 * 1024];  // 128 KB
  __shared__ __align__(16) unsigned short Hs[16 * 1024];        // 32 KB h stage; gx aliased (phase-separated)
  float* gx = (float*)(void*)Hs;                                // [4][64*5] padded floats, 5120 B
  const int tid = threadIdx.x, lane = tid & 63, wave = tid >> 6;
  const int wg = blockIdx.x, gb = wg >> 6, ug = wg & 63;
  const int li = lane & 15, kq = lane >> 4;

  // ---- W_hh slice -> LDS bf16, swizzled: byte = (wave*16+u)*2048 + (2k ^ ((u&7)<<4))
  for (int it = 0; it < 64; ++it) {
    int idx = it * 256 + lane * 4;
    int u = idx >> 10, k = idx & 1023;
    const float4 w = *(const float4*)&Whh[((size_t)(wave * H_ + ug * 16 + u)) * H_ + k];
    ushort4 p; p.x = f2bf(w.x); p.y = f2bf(w.y); p.z = f2bf(w.z); p.w = f2bf(w.w);
    *(ushort4*)((char*)Wlds + (size_t)(wave * 16 + u) * 2048 + ((2 * k) ^ ((u & 7) << 4))) = p;
  }
  // ---- init h buffer 1 (read at t=0) with bypass stores; c state in a register
  {
    int b = gb * 16 + (tid >> 4), u = ug * 16 + (tid & 15);
    st_u16_cc(&h_pp[(size_t)(B_ + b) * H_ + u], f2bf(h0[(size_t)b * H_ + u]));
  }
  const int bm = gb * 16 + kq * 4 + wave;   // this thread's (batch,unit) in the update phase
  const int uu = ug * 16 + li;
  float c_st = c0[(size_t)bm * H_ + uu];

  unsigned ep = 1;
  auto gbar = [&](unsigned e) {
    __syncthreads();                        // per-wave vmcnt(0) drain before s_barrier
    if (wave == 0) {
      asm volatile("s_waitcnt vmcnt(0) lgkmcnt(0)" ::: "memory");
      if (lane == 0) st_u32_cc(&flags[wg], e);
      unsigned v;
      do {
        __builtin_amdgcn_s_sleep(1);
        v = ld_u32_cc(&flags[(gb << 6) + lane]);
      } while (__any((int)(v < e)));
    }
    __syncthreads();
  };
  gbar(ep); ep++;

  const char* bbase = (const char*)Wlds + (size_t)(wave * 16 + li) * 2048;
  const char* abase = (const char*)Hs + (size_t)li * 2048;
  const int lxor = (li & 7) << 4;
  const int srow_r = tid >> 4, sseg = tid & 15;
  const int sswz = (srow_r & 7) << 4;

  for (int t = 0; t < T_; ++t) {
    const unsigned short* hrd = h_pp + (size_t)((t & 1) ^ 1) * (B_ * H_);
    unsigned short* hwr = h_pp + (size_t)(t & 1) * (B_ * H_);

    // xg for this step (cached loads, overlap the stage round-trip)
    float xv[4];
#pragma unroll
    for (int r = 0; r < 4; ++r)
      xv[r] = bf2f(xg[((size_t)(gb * 16 + kq * 4 + r) * T_ + t) * (4 * H_) + (size_t)wave * H_ + uu]);

    // ---- cooperative h stage: 256 threads, one round trip, bypass loads, swizzled LDS
    {
      const char* srow = (const char*)(hrd + (size_t)(gb * 16 + srow_r) * H_);
      char* drow = (char*)Hs + (size_t)srow_r * 2048;
      ulonglong2 tmp[8];
#pragma unroll
      for (int m = 0; m < 8; ++m) {
        int gofs = sseg * 128 + (((m + sseg) & 7) << 4);   // rotation spreads LDS banks
        tmp[m].x = ld_u64_cc(srow + gofs);
        tmp[m].y = ld_u64_cc(srow + gofs + 8);
      }
      __builtin_amdgcn_sched_barrier(0);
      asm volatile("" ::: "memory");
#pragma unroll
      for (int m = 0; m < 8; ++m) {
        int gofs = sseg * 128 + (((m + sseg) & 7) << 4);
        *(ulonglong2*)(drow + (gofs ^ sswz)) = tmp[m];
      }
    }
    __syncthreads();

    // ---- gate MFMA chain: wave = gate, dual accumulators
    f32x4 acc0 = {0.f, 0.f, 0.f, 0.f}, acc1 = {0.f, 0.f, 0.f, 0.f};
#pragma unroll
    for (int ks = 0; ks < 32; ks += 2) {
      bf16x8 a0 = *(const bf16x8*)(abase + ((ks * 64 + kq * 16) ^ lxor));
      bf16x8 b0 = *(const bf16x8*)(bbase + ((ks * 64 + kq * 16) ^ lxor));
      acc0 = __builtin_amdgcn_mfma_f32_16x16x32_bf16(a0, b0, acc0, 0, 0, 0);
      bf16x8 a1 = *(const bf16x8*)(abase + (((ks + 1) * 64 + kq * 16) ^ lxor));
      bf16x8 b1 = *(const bf16x8*)(bbase + (((ks + 1) * 64 + kq * 16) ^ lxor));
      acc1 = __builtin_amdgcn_mfma_f32_16x16x32_bf16(a1, b1, acc1, 0, 0, 0);
    }
    __syncthreads();                       // all Hs reads done before gx overwrites it

#pragma unroll
    for (int r = 0; r < 4; ++r)
      gx[wave * 320 + lane * 5 + r] = acc0[r] + acc1[r] + xv[r];
    __syncthreads();

    // ---- cell update: all 4 waves, r = wave
    {
      float gi = gx[0 * 320 + lane * 5 + wave];
      float gf = gx[1 * 320 + lane * 5 + wave];
      float gg = gx[2 * 320 + lane * 5 + wave];
      float go = gx[3 * 320 + lane * 5 + wave];
      float ci = sigmf(gf) * c_st + sigmf(gi) * tanh_f(gg);
      c_st = ci;
      float h = sigmf(go) * tanh_f(ci);
      st_u16_cc(&hwr[(size_t)bm * H_ + uu], f2bf(h));
      if (out_seq) out_seq[((size_t)bm * T_ + t) * H_ + uu] = f2bf(h);
      if (t == T_ - 1) {
        hT[(size_t)bm * H_ + uu] = h;
        cT[(size_t)bm * H_ + uu] = ci;
      }
    }
    gbar(ep); ep++;
  }
}

// ---------------- launcher ----------------

extern "C" void kernel_launch(void* const* d_in, const int* in_sizes, int n_in,
                              void* d_out, int out_size, void* d_ws, size_t ws_size,
                              hipStream_t stream) {
  const float* seq  = (const float*)d_in[0];
  const float* Wi2h = (const float*)d_in[1];
  const float* bi2h = (const float*)d_in[2];
  const float* Wih  = (const float*)d_in[3];
  const float* Whh  = (const float*)d_in[4];
  const float* bih  = (const float*)d_in[5];
  const float* bhh  = (const float*)d_in[6];
  const float* Wh2o = (const float*)d_in[7];
  const float* bh2o = (const float*)d_in[8];
  const float* h0   = (const float*)d_in[9];
  const float* c0   = (const float*)d_in[10];
  float* outF = (float*)d_out;

  size_t off = 0;
  auto nb = [&](size_t bytes) { size_t r = off; off += (bytes + 255) & ~(size_t)255; return r; };
  unsigned short* xbf   = (unsigned short*)((char*)d_ws + nb((size_t)B_ * T_ * H_ * 2));       // 32MB
  unsigned short* seqA  = (unsigned short*)((char*)d_ws + nb((size_t)B_ * T_ * H_ * 2));       // 32MB
  unsigned short* xg    = (unsigned short*)((char*)d_ws + nb((size_t)B_ * T_ * 4 * H_ * 2));   // 128MB
  unsigned short* Wihb  = (unsigned short*)((char*)d_ws + nb((size_t)L_ * 4 * H_ * H_ * 2));   // 24MB
  unsigned short* Wh2ob = (unsigned short*)((char*)d_ws + nb((size_t)AS_ * H_ * 2));
  unsigned short* Wt    = (unsigned short*)((char*)d_ws + nb((size_t)AS_ * H_ * 2));
  float*          bsum  = (float*)((char*)d_ws + nb((size_t)L_ * 4 * H_ * 4));
  unsigned short* h_pp  = (unsigned short*)((char*)d_ws + nb((size_t)2 * B_ * H_ * 2));
  unsigned*       flg   = (unsigned*)((char*)d_ws + nb((size_t)L_ * 256 * 4));
  (void)ws_size; (void)in_sizes; (void)n_in; (void)out_size;

  const int WLAYER = 4 * H_ * H_;

  k_zero<<<3, 256, 0, stream>>>(flg, L_ * 256);
  k_wt_i2h<<<(AS_ * H_ + 255) / 256, 256, 0, stream>>>(Wi2h, bi2h, Wt);
  k_f2b<<<(L_ * WLAYER + 255) / 256, 256, 0, stream>>>(Wih, Wihb, L_ * WLAYER);
  k_f2b<<<(AS_ * H_ + 255) / 256, 256, 0, stream>>>(Wh2o, Wh2ob, AS_ * H_);
  k_bias<<<(L_ * 4 * H_ + 255) / 256, 256, 0, stream>>>(bih, bhh, bsum, L_ * 4 * H_);
  k_gather<<<B_ * T_, 128, 0, stream>>>(seq, Wt, xbf);

  // out = x @ W_h2O^T + b  (faithful to reference bug: uses x, not LSTM output)
  k_gemm<0><<<dim3(B_ * T_ / 128, AS_ / 128), 256, 0, stream>>>(
      xbf, Wh2ob, bh2o, (void*)outF, B_ * T_, AS_, H_);

  float* hT_base = outF + (size_t)B_ * T_ * AS_;
  float* cT_base = hT_base + (size_t)L_ * B_ * H_;

  for (int l = 0; l < L_; ++l) {
    const unsigned short* Ain = (l == 0) ? xbf : (l == 1) ? seqA : xbf;
    unsigned short* oseq = (l == 0) ? seqA : (l == 1) ? xbf : nullptr;
    k_gemm<1><<<dim3(B_ * T_ / 128, 4 * H_ / 128), 256, 0, stream>>>(
        Ain, Wihb + (size_t)l * WLAYER, bsum + (size_t)l * 4 * H_, (void*)xg,
        B_ * T_, 4 * H_, H_);
    k_scan<<<256, 256, 0, stream>>>(
        xg, Whh + (size_t)l * WLAYER, h_pp, oseq,
        hT_base + (size_t)l * B_ * H_, cT_base + (size_t)l * B_ * H_,
        h0 + (size_t)l * B_ * H_, c0 + (size_t)l * B_ * H_,
        flg + (size_t)l * 256);
  }
}

// Round 5
// 7322.388 us; speedup vs baseline: 2.1463x; 1.0055x over previous
//
#include <hip/hip_runtime.h>
#include <stdint.h>
#include <stddef.h>

#define B_  64
#define T_  256
#define H_  1024
#define AS_ 128
#define L_  3

typedef __attribute__((ext_vector_type(8))) short bf16x8;
typedef __attribute__((ext_vector_type(4))) float f32x4;

__device__ __forceinline__ unsigned short f2bf(float f) {
  union { float f; unsigned u; } x; x.f = f;
  unsigned r = x.u + 0x7fffu + ((x.u >> 16) & 1u);   // RNE
  return (unsigned short)(r >> 16);
}
__device__ __forceinline__ float bf2f(unsigned short s) {
  union { unsigned u; float f; } x; x.u = ((unsigned)s) << 16; return x.f;
}
__device__ __forceinline__ float sigmf(float x) { return 1.0f / (1.0f + __expf(-x)); }
__device__ __forceinline__ float tanh_f(float x) {
  x = fminf(fmaxf(x, -15.0f), 15.0f);
  float e = __expf(2.0f * x);
  return (e - 1.0f) / (e + 1.0f);
}

// ---- device-coherent (MALL) accessors: relaxed agent atomics — PROVEN in R2 ----
__device__ __forceinline__ unsigned long long ld_u64_cc(const void* p) {
  return __hip_atomic_load((const unsigned long long*)p, __ATOMIC_RELAXED, __HIP_MEMORY_SCOPE_AGENT);
}
__device__ __forceinline__ void st_u16_cc(unsigned short* p, unsigned short v) {
  __hip_atomic_store(p, v, __ATOMIC_RELAXED, __HIP_MEMORY_SCOPE_AGENT);
}
__device__ __forceinline__ void st_u32_cc(unsigned* p, unsigned v) {
  __hip_atomic_store(p, v, __ATOMIC_RELAXED, __HIP_MEMORY_SCOPE_AGENT);
}
__device__ __forceinline__ unsigned ld_u32_cc(const unsigned* p) {
  return __hip_atomic_load(p, __ATOMIC_RELAXED, __HIP_MEMORY_SCOPE_AGENT);
}

// ---------------- tiny utility kernels ----------------

__global__ void k_zero(unsigned* p, int n) {
  int i = blockIdx.x * 256 + threadIdx.x;
  if (i < n) st_u32_cc(p + i, 0u);
}

__global__ void k_wt_i2h(const float* __restrict__ W, const float* __restrict__ b,
                         unsigned short* __restrict__ Wt) {
  int id = blockIdx.x * 256 + threadIdx.x;
  if (id >= AS_ * H_) return;
  int a = id >> 10, h = id & 1023;
  Wt[id] = f2bf(W[h * AS_ + a] + b[h]);
}

__global__ void k_f2b(const float* __restrict__ s, unsigned short* __restrict__ d, int n) {
  int i = blockIdx.x * 256 + threadIdx.x;
  if (i < n) d[i] = f2bf(s[i]);
}

__global__ void k_bias(const float* __restrict__ bi, const float* __restrict__ bh,
                       float* __restrict__ o, int n) {
  int i = blockIdx.x * 256 + threadIdx.x;
  if (i < n) o[i] = bi[i] + bh[i];
}

__global__ __launch_bounds__(128) void k_gather(const float* __restrict__ seq,
                                                const unsigned short* __restrict__ Wt,
                                                unsigned short* __restrict__ xbf) {
  __shared__ int sidx;
  const int bt = blockIdx.x, tid = threadIdx.x;
  if (seq[(size_t)bt * AS_ + tid] > 0.5f) sidx = tid;
  __syncthreads();
  const uint4* s = (const uint4*)(Wt + (size_t)sidx * H_);
  uint4* d = (uint4*)(xbf + (size_t)bt * H_);
  d[tid] = s[tid];
}

// ---------------- MFMA GEMM (unchanged, proven) ----------------

__device__ __forceinline__ void gld16(const void* g, void* l) {
  __builtin_amdgcn_global_load_lds((const __attribute__((address_space(1))) unsigned int*)g,
                                   (__attribute__((address_space(3))) unsigned int*)l,
                                   16, 0, 0);
}

template <int OUT_BF16>
__global__ __launch_bounds__(256) void k_gemm(const unsigned short* __restrict__ A,
                                              const unsigned short* __restrict__ Bm,
                                              const float* __restrict__ bias,
                                              void* __restrict__ Cout,
                                              int M, int N, int K) {
  __shared__ __align__(16) unsigned short As[128 * 32];
  __shared__ __align__(16) unsigned short Bs[128 * 32];
  const int tid = threadIdx.x, lane = tid & 63, wv = tid >> 6;
  const int m0 = blockIdx.x * 128, n0 = blockIdx.y * 128;
  const int wr = wv >> 1, wc = wv & 1;
  const int kg = lane >> 4, li = lane & 15;
  f32x4 acc[4][4] = {};

  for (int k0 = 0; k0 < K; k0 += 32) {
    for (int i = 0; i < 2; ++i) {
      int c0 = i * 256 + wv * 64;
      int cid = c0 + lane;
      int row = cid >> 2, lc = cid & 3;
      int sc = lc ^ ((row >> 1) & 3);
      gld16(A + (size_t)(m0 + row) * K + k0 + sc * 8, (char*)As + (size_t)c0 * 16);
      gld16(Bm + (size_t)(n0 + row) * K + k0 + sc * 8, (char*)Bs + (size_t)c0 * 16);
    }
    __syncthreads();
    bf16x8 af[4], bfm[4];
#pragma unroll
    for (int mi = 0; mi < 4; ++mi) {
      int row = wr * 64 + mi * 16 + li;
      int pc = kg ^ ((row >> 1) & 3);
      af[mi] = *(const bf16x8*)((const char*)As + row * 64 + pc * 16);
    }
#pragma unroll
    for (int ni = 0; ni < 4; ++ni) {
      int row = wc * 64 + ni * 16 + li;
      int pc = kg ^ ((row >> 1) & 3);
      bfm[ni] = *(const bf16x8*)((const char*)Bs + row * 64 + pc * 16);
    }
#pragma unroll
    for (int mi = 0; mi < 4; ++mi)
#pragma unroll
      for (int ni = 0; ni < 4; ++ni)
        acc[mi][ni] = __builtin_amdgcn_mfma_f32_16x16x32_bf16(af[mi], bfm[ni], acc[mi][ni], 0, 0, 0);
    __syncthreads();
  }

#pragma unroll
  for (int mi = 0; mi < 4; ++mi)
#pragma unroll
    for (int ni = 0; ni < 4; ++ni)
#pragma unroll
      for (int r = 0; r < 4; ++r) {
        int row = m0 + wr * 64 + mi * 16 + kg * 4 + r;
        int col = n0 + wc * 64 + ni * 16 + li;
        float v = acc[mi][ni][r] + bias[col];
        if (OUT_BF16) ((unsigned short*)Cout)[(size_t)row * N + col] = f2bf(v);
        else          ((float*)Cout)[(size_t)row * N + col] = v;
      }
}

// ---------------- persistent LSTM scan (R2 structure + 8x h replication) ----------------
// 256 wgs (1/CU). wg = (gb: batch group of 16, ug: unit group of 16).
// h is stored 8x replicated in MALL; consumer wg reads replica (ug&7), so each
// MALL line is read by 8 wgs instead of 64 (de-hotspot). All cross-wg traffic
// uses relaxed agent atomics (proven); barriers/flags identical to R2.

__global__ __launch_bounds__(256, 1) void k_scan(
    const unsigned short* __restrict__ xg,    // [B*T][4H] bf16 (bias folded)
    const float* __restrict__ Whh,            // [4H][H] f32
    unsigned short* __restrict__ h_rep,       // [8][2][B][H] bf16 (MALL, replicated)
    unsigned short* __restrict__ out_seq,     // [B*T][H] bf16 or null
    float* __restrict__ hT, float* __restrict__ cT,
    const float* __restrict__ h0, const float* __restrict__ c0,
    unsigned* __restrict__ gflag) {           // [256] this layer (MALL)
  __shared__ __align__(16) unsigned short Wlds[4 * 16 * 1024];  // 128 KB
  __shared__ __align__(16) unsigned short Hs[16 * 1024];        // 32 KB; gx aliased
  float* gx = (float*)(void*)Hs;
  const int tid = threadIdx.x, lane = tid & 63, wave = tid >> 6;
  const int wg = blockIdx.x, gb = wg >> 6, ug = wg & 63;
  const int li = lane & 15, kq = lane >> 4;
  const int rep = ug & 7;                     // this wg's read replica

  // ---- W_hh slice -> LDS bf16, swizzled: byte = (wave*16+u)*2048 + (2k ^ ((u&7)<<4))
  for (int it = 0; it < 64; ++it) {
    int idx = it * 256 + lane * 4;
    int u = idx >> 10, k = idx & 1023;
    const float4 w = *(const float4*)&Whh[((size_t)(wave * H_ + ug * 16 + u)) * H_ + k];
    ushort4 p; p.x = f2bf(w.x); p.y = f2bf(w.y); p.z = f2bf(w.z); p.w = f2bf(w.w);
    *(ushort4*)((char*)Wlds + (size_t)(wave * 16 + u) * 2048 + ((2 * k) ^ ((u & 7) << 4))) = p;
  }
  // ---- init h parity-1 (read at t=0) in all 8 replicas; c state in a register
  {
    int b = gb * 16 + (tid >> 4), u = ug * 16 + (tid & 15);
    unsigned short v = f2bf(h0[(size_t)b * H_ + u]);
#pragma unroll
    for (int r8 = 0; r8 < 8; ++r8)
      st_u16_cc(&h_rep[(((size_t)r8 * 2 + 1) * B_ + b) * H_ + u], v);
  }
  const int bm = gb * 16 + kq * 4 + wave;     // this thread's (batch,unit) in update phase
  const int uu = ug * 16 + li;
  float c_st = c0[(size_t)bm * H_ + uu];

  unsigned ep = 1;
  auto gbar = [&](unsigned e) {
    __syncthreads();                          // per-wave vmcnt(0) drain before s_barrier
    if (wave == 0) {
      asm volatile("s_waitcnt vmcnt(0) lgkmcnt(0)" ::: "memory");
      if (lane == 0) st_u32_cc(&gflag[wg], e);
      unsigned v;
      do {
        __builtin_amdgcn_s_sleep(1);
        v = ld_u32_cc(&gflag[(gb << 6) + lane]);
      } while (__any((int)(v < e)));
    }
    __syncthreads();
  };
  gbar(ep); ep++;

  const char* bbase = (const char*)Wlds + (size_t)(wave * 16 + li) * 2048;
  const char* abase = (const char*)Hs + (size_t)li * 2048;
  const int lxor = (li & 7) << 4;
  const int srow_r = tid >> 4, sseg = tid & 15;
  const int sswz = (srow_r & 7) << 4;

  for (int t = 0; t < T_; ++t) {
    const unsigned short* hrd = h_rep + (((size_t)rep * 2 + ((t & 1) ^ 1)) * B_) * H_;
    const size_t wr_par = (size_t)(t & 1);

    // xg for this step (cached loads, overlap the stage round-trip)
    float xv[4];
#pragma unroll
    for (int r = 0; r < 4; ++r)
      xv[r] = bf2f(xg[((size_t)(gb * 16 + kq * 4 + r) * T_ + t) * (4 * H_) + (size_t)wave * H_ + uu]);

    // ---- cooperative h stage: 256 threads, bypass loads from own replica, swizzled LDS
    {
      const char* srow = (const char*)(hrd + (size_t)(gb * 16 + srow_r) * H_);
      char* drow = (char*)Hs + (size_t)srow_r * 2048;
      ulonglong2 tmp[8];
#pragma unroll
      for (int m = 0; m < 8; ++m) {
        int gofs = sseg * 128 + (((m + sseg) & 7) << 4);   // rotation spreads LDS banks
        tmp[m].x = ld_u64_cc(srow + gofs);
        tmp[m].y = ld_u64_cc(srow + gofs + 8);
      }
      __builtin_amdgcn_sched_barrier(0);
      asm volatile("" ::: "memory");
#pragma unroll
      for (int m = 0; m < 8; ++m) {
        int gofs = sseg * 128 + (((m + sseg) & 7) << 4);
        *(ulonglong2*)(drow + (gofs ^ sswz)) = tmp[m];
      }
    }
    __syncthreads();

    // ---- gate MFMA chain: wave = gate, dual accumulators
    f32x4 acc0 = {0.f, 0.f, 0.f, 0.f}, acc1 = {0.f, 0.f, 0.f, 0.f};
#pragma unroll
    for (int ks = 0; ks < 32; ks += 2) {
      bf16x8 a0 = *(const bf16x8*)(abase + ((ks * 64 + kq * 16) ^ lxor));
      bf16x8 b0 = *(const bf16x8*)(bbase + ((ks * 64 + kq * 16) ^ lxor));
      acc0 = __builtin_amdgcn_mfma_f32_16x16x32_bf16(a0, b0, acc0, 0, 0, 0);
      bf16x8 a1 = *(const bf16x8*)(abase + (((ks + 1) * 64 + kq * 16) ^ lxor));
      bf16x8 b1 = *(const bf16x8*)(bbase + (((ks + 1) * 64 + kq * 16) ^ lxor));
      acc1 = __builtin_amdgcn_mfma_f32_16x16x32_bf16(a1, b1, acc1, 0, 0, 0);
    }
    __syncthreads();                          // Hs reads done before gx overwrites

#pragma unroll
    for (int r = 0; r < 4; ++r)
      gx[wave * 320 + lane * 5 + r] = acc0[r] + acc1[r] + xv[r];
    __syncthreads();

    // ---- cell update: all 4 waves, r = wave; write h to all 8 replicas
    {
      float gi = gx[0 * 320 + lane * 5 + wave];
      float gf = gx[1 * 320 + lane * 5 + wave];
      float gg = gx[2 * 320 + lane * 5 + wave];
      float go = gx[3 * 320 + lane * 5 + wave];
      float ci = sigmf(gf) * c_st + sigmf(gi) * tanh_f(gg);
      c_st = ci;
      float h = sigmf(go) * tanh_f(ci);
      unsigned short hbf = f2bf(h);
#pragma unroll
      for (int r8 = 0; r8 < 8; ++r8)
        st_u16_cc(&h_rep[(((size_t)r8 * 2 + wr_par) * B_ + bm) * H_ + uu], hbf);
      if (out_seq) out_seq[((size_t)bm * T_ + t) * H_ + uu] = hbf;
      if (t == T_ - 1) {
        hT[(size_t)bm * H_ + uu] = h;
        cT[(size_t)bm * H_ + uu] = ci;
      }
    }
    gbar(ep); ep++;
  }
}

// ---------------- launcher ----------------

extern "C" void kernel_launch(void* const* d_in, const int* in_sizes, int n_in,
                              void* d_out, int out_size, void* d_ws, size_t ws_size,
                              hipStream_t stream) {
  const float* seq  = (const float*)d_in[0];
  const float* Wi2h = (const float*)d_in[1];
  const float* bi2h = (const float*)d_in[2];
  const float* Wih  = (const float*)d_in[3];
  const float* Whh  = (const float*)d_in[4];
  const float* bih  = (const float*)d_in[5];
  const float* bhh  = (const float*)d_in[6];
  const float* Wh2o = (const float*)d_in[7];
  const float* bh2o = (const float*)d_in[8];
  const float* h0   = (const float*)d_in[9];
  const float* c0   = (const float*)d_in[10];
  float* outF = (float*)d_out;

  size_t off = 0;
  auto nb = [&](size_t bytes) { size_t r = off; off += (bytes + 255) & ~(size_t)255; return r; };
  unsigned short* xbf   = (unsigned short*)((char*)d_ws + nb((size_t)B_ * T_ * H_ * 2));
  unsigned short* seqA  = (unsigned short*)((char*)d_ws + nb((size_t)B_ * T_ * H_ * 2));
  unsigned short* xg    = (unsigned short*)((char*)d_ws + nb((size_t)B_ * T_ * 4 * H_ * 2));
  unsigned short* Wihb  = (unsigned short*)((char*)d_ws + nb((size_t)L_ * 4 * H_ * H_ * 2));
  unsigned short* Wh2ob = (unsigned short*)((char*)d_ws + nb((size_t)AS_ * H_ * 2));
  unsigned short* Wt    = (unsigned short*)((char*)d_ws + nb((size_t)AS_ * H_ * 2));
  float*          bsum  = (float*)((char*)d_ws + nb((size_t)L_ * 4 * H_ * 4));
  unsigned short* h_rep = (unsigned short*)((char*)d_ws + nb((size_t)8 * 2 * B_ * H_ * 2)); // 2MB
  unsigned*       flg   = (unsigned*)((char*)d_ws + nb((size_t)L_ * 256 * 4));
  (void)ws_size; (void)in_sizes; (void)n_in; (void)out_size;

  const int WLAYER = 4 * H_ * H_;

  k_zero<<<3, 256, 0, stream>>>(flg, L_ * 256);
  k_wt_i2h<<<(AS_ * H_ + 255) / 256, 256, 0, stream>>>(Wi2h, bi2h, Wt);
  k_f2b<<<(L_ * WLAYER + 255) / 256, 256, 0, stream>>>(Wih, Wihb, L_ * WLAYER);
  k_f2b<<<(AS_ * H_ + 255) / 256, 256, 0, stream>>>(Wh2o, Wh2ob, AS_ * H_);
  k_bias<<<(L_ * 4 * H_ + 255) / 256, 256, 0, stream>>>(bih, bhh, bsum, L_ * 4 * H_);
  k_gather<<<B_ * T_, 128, 0, stream>>>(seq, Wt, xbf);

  // out = x @ W_h2O^T + b  (faithful to reference bug: uses x, not LSTM output)
  k_gemm<0><<<dim3(B_ * T_ / 128, AS_ / 128), 256, 0, stream>>>(
      xbf, Wh2ob, bh2o, (void*)outF, B_ * T_, AS_, H_);

  float* hT_base = outF + (size_t)B_ * T_ * AS_;
  float* cT_base = hT_base + (size_t)L_ * B_ * H_;

  for (int l = 0; l < L_; ++l) {
    const unsigned short* Ain = (l == 0) ? xbf : (l == 1) ? seqA : xbf;
    unsigned short* oseq = (l == 0) ? seqA : (l == 1) ? xbf : nullptr;
    k_gemm<1><<<dim3(B_ * T_ / 128, 4 * H_ / 128), 256, 0, stream>>>(
        Ain, Wihb + (size_t)l * WLAYER, bsum + (size_t)l * 4 * H_, (void*)xg,
        B_ * T_, 4 * H_, H_);
    k_scan<<<256, 256, 0, stream>>>(
        xg, Whh + (size_t)l * WLAYER, h_rep, oseq,
        hT_base + (size_t)l * B_ * H_, cT_base + (size_t)l * B_ * H_,
        h0 + (size_t)l * B_ * H_, c0 + (size_t)l * B_ * H_,
        flg + (size_t)l * 256);
  }
}